// Round 8
// baseline (6154.599 us; speedup 1.0000x reference)
//
#include <hip/hip_runtime.h>
#include <math.h>

#define TPB 256
#define BSH 7                  // 128 nodes per bucket
#define NPB (1 << BSH)         // nodes per bucket
#define BMAX 1024              // max buckets (N <= 131072)
#define EPB 4096               // edges per block in hist/bucket passes

// ---------------- edge bucketing (no global random atomics) ----------------

// pass A: coarse histogram of dst by bucket
__global__ __launch_bounds__(TPB) void k_hist(const int* __restrict__ dst,
                                              int* __restrict__ bucketCnt,
                                              int nE, int nbuck) {
  __shared__ int h[BMAX];
  for (int i = threadIdx.x; i < BMAX; i += TPB) h[i] = 0;
  __syncthreads();
  int base = blockIdx.x * EPB;
  for (int i = threadIdx.x; i < EPB; i += TPB) {
    int e = base + i;
    if (e < nE) atomicAdd(&h[dst[e] >> BSH], 1);
  }
  __syncthreads();
  for (int i = threadIdx.x; i < nbuck; i += TPB)
    if (h[i]) atomicAdd(&bucketCnt[i], h[i]);
}

// pass B: scan bucket counts -> bOff[nbuck+1], init gCur
__global__ __launch_bounds__(BMAX) void k_bscan(const int* __restrict__ bucketCnt,
                                                int* __restrict__ bOff,
                                                int* __restrict__ gCur,
                                                int nbuck) {
  __shared__ int sd[BMAX];
  int t = threadIdx.x;
  int v = (t < nbuck) ? bucketCnt[t] : 0;
  sd[t] = v;
  __syncthreads();
  for (int off = 1; off < BMAX; off <<= 1) {
    int add = (t >= off) ? sd[t - off] : 0;
    __syncthreads();
    sd[t] += add;
    __syncthreads();
  }
  if (t < nbuck) {
    bOff[t + 1] = sd[t];
    gCur[t] = sd[t] - v;     // exclusive prefix
  }
  if (t == 0) bOff[0] = 0;
}

// pass C: scatter packed (src | dlocal<<20) into bucket-sorted pairBuf
__global__ __launch_bounds__(TPB) void k_bucket(const int* __restrict__ src,
                                                const int* __restrict__ dst,
                                                int* __restrict__ gCur,
                                                int* __restrict__ pairBuf,
                                                int nE, int nbuck) {
  __shared__ int   hist[BMAX];
  __shared__ int   baseL[BMAX];
  __shared__ int   sp[EPB];
  __shared__ short sbk[EPB];
  for (int i = threadIdx.x; i < BMAX; i += TPB) hist[i] = 0;
  __syncthreads();
  int cb = blockIdx.x * EPB;
  for (int i = threadIdx.x; i < EPB; i += TPB) {
    int e = cb + i;
    if (e < nE) {
      int s = src[e], d = dst[e];
      int b = d >> BSH;
      sp[i]  = s | ((d & (NPB - 1)) << 20);
      sbk[i] = (short)b;
      atomicAdd(&hist[b], 1);
    } else sbk[i] = -1;
  }
  __syncthreads();
  for (int i = threadIdx.x; i < nbuck; i += TPB)
    baseL[i] = hist[i] ? atomicAdd(&gCur[i], hist[i]) : 0;
  __syncthreads();
  for (int i = threadIdx.x; i < BMAX; i += TPB) hist[i] = 0;  // reuse as cursor
  __syncthreads();
  for (int i = threadIdx.x; i < EPB; i += TPB) {
    int b = sbk[i];
    if (b >= 0) {
      int r = atomicAdd(&hist[b], 1);
      pairBuf[baseL[b] + r] = sp[i];
    }
  }
}

// pass D: per-bucket degree histogram -> dinv (no CSR ranking needed)
__global__ __launch_bounds__(TPB) void k_deg(const int* __restrict__ pairBuf,
                                             const int* __restrict__ bOff,
                                             float* __restrict__ dinv, int n) {
  __shared__ int h[NPB];
  int t = threadIdx.x;
  int b = blockIdx.x;
  if (t < NPB) h[t] = 0;
  __syncthreads();
  int p0 = bOff[b], p1 = bOff[b + 1];
  for (int i = p0 + t; i < p1; i += TPB)
    atomicAdd(&h[pairBuf[i] >> 20], 1);
  __syncthreads();
  if (t < NPB) {
    int node = (b << BSH) + t;
    if (node < n) dinv[node] = rsqrtf((float)(h[t] + 1));  // +1 self loop
  }
}

// ---------------- per-layer kernels (dense N x 64 row-major layout) ----------------

// HWS[n][c] = (act(H[n]) @ W)[c] * dinv[n]
__global__ __launch_bounds__(TPB, 4) void k_gemm(const float* __restrict__ H,
                                                 const float* __restrict__ W,
                                                 const float* __restrict__ dinv,
                                                 float* __restrict__ HWS,
                                                 int relu, int rows) {
  __shared__ float Wl[64 * 64];     // [k][c]
  __shared__ float Hl[64][68];      // [r][k], padded
  const int tid = threadIdx.x;
  const int c0 = (tid & 15) * 4;
  const int r0 = (tid >> 4) * 4;
  const int row0 = blockIdx.x * 64;

  for (int i = tid; i < 64 * 16; i += TPB)
    ((float4*)Wl)[i] = ((const float4*)W)[i];

  for (int i = tid; i < 64 * 16; i += TPB) {
    int r = i >> 4, q = i & 15;
    int gr = row0 + r;
    float4 v = make_float4(0.f, 0.f, 0.f, 0.f);
    if (gr < rows) v = ((const float4*)(H + (size_t)gr * 64))[q];
    if (relu) {
      v.x = fmaxf(v.x, 0.f); v.y = fmaxf(v.y, 0.f);
      v.z = fmaxf(v.z, 0.f); v.w = fmaxf(v.w, 0.f);
    }
    *(float4*)&Hl[r][q * 4] = v;
  }
  __syncthreads();

  float acc[4][4] = {{0.f,0.f,0.f,0.f},{0.f,0.f,0.f,0.f},
                     {0.f,0.f,0.f,0.f},{0.f,0.f,0.f,0.f}};
#pragma unroll 4
  for (int k = 0; k < 64; ++k) {
    float4 w = *(const float4*)&Wl[k * 64 + c0];
    float h0 = Hl[r0 + 0][k];
    float h1 = Hl[r0 + 1][k];
    float h2 = Hl[r0 + 2][k];
    float h3 = Hl[r0 + 3][k];
    acc[0][0] = fmaf(h0, w.x, acc[0][0]); acc[0][1] = fmaf(h0, w.y, acc[0][1]);
    acc[0][2] = fmaf(h0, w.z, acc[0][2]); acc[0][3] = fmaf(h0, w.w, acc[0][3]);
    acc[1][0] = fmaf(h1, w.x, acc[1][0]); acc[1][1] = fmaf(h1, w.y, acc[1][1]);
    acc[1][2] = fmaf(h1, w.z, acc[1][2]); acc[1][3] = fmaf(h1, w.w, acc[1][3]);
    acc[2][0] = fmaf(h2, w.x, acc[2][0]); acc[2][1] = fmaf(h2, w.y, acc[2][1]);
    acc[2][2] = fmaf(h2, w.z, acc[2][2]); acc[2][3] = fmaf(h2, w.w, acc[2][3]);
    acc[3][0] = fmaf(h3, w.x, acc[3][0]); acc[3][1] = fmaf(h3, w.y, acc[3][1]);
    acc[3][2] = fmaf(h3, w.z, acc[3][2]); acc[3][3] = fmaf(h3, w.w, acc[3][3]);
  }

#pragma unroll
  for (int i = 0; i < 4; ++i) {
    int gr = row0 + r0 + i;
    if (gr < rows) {
      float s = dinv[gr];
      float4 o = make_float4(acc[i][0] * s, acc[i][1] * s,
                             acc[i][2] * s, acc[i][3] * s);
      *(float4*)&HWS[(size_t)gr * 64 + c0] = o;
    }
  }
}

// Edge-parallel aggregation with LDS accumulators.
// Block = dst bucket (128 nodes). acc[dl][ch] in LDS (32KB), channel-rotated
// by 4*dl so concurrent groups (different dl) hit different banks.
// 16-lane group per edge: lane gl reads float4 HWS[src*16+gl] -> full 256B
// row = 4 full-line L3/L2 requests per edge; 4-edge unroll for MLP.
__global__ __launch_bounds__(TPB) void k_agg(const float* __restrict__ HWS,
                                             const int* __restrict__ pairBuf,
                                             const int* __restrict__ bOff,
                                             const float* __restrict__ dinv,
                                             const float* __restrict__ bias,
                                             float* __restrict__ OUT, int n) {
  __shared__ float acc[NPB * 64];
  const int b = blockIdx.x;
  const int tid = threadIdx.x;
  const int node0 = b << BSH;

  // init with self-loop term (HWS already dinv-prescaled)
  for (int i = tid; i < NPB * 64; i += TPB) {
    int dl = i >> 6, c = i & 63;
    int node = node0 + dl;
    float v = (node < n) ? HWS[(size_t)node * 64 + c] : 0.f;
    acc[dl * 64 + ((c + dl * 4) & 63)] = v;
  }
  __syncthreads();

  const int p0 = bOff[b], p1 = bOff[b + 1];
  const int g  = tid >> 4;      // group 0..15 (one edge per group)
  const int gl = tid & 15;      // lane-in-group: float4 quadrant of the row
  const float4* __restrict__ tab = (const float4*)HWS;

  int e = p0 + g;
  for (; e + 48 < p1; e += 64) {
    int pa = pairBuf[e];
    int pb = pairBuf[e + 16];
    int pc = pairBuf[e + 32];
    int pd = pairBuf[e + 48];
    float4 va = tab[(size_t)(pa & 0xFFFFF) * 16 + gl];
    float4 vb = tab[(size_t)(pb & 0xFFFFF) * 16 + gl];
    float4 vc = tab[(size_t)(pc & 0xFFFFF) * 16 + gl];
    float4 vd = tab[(size_t)(pd & 0xFFFFF) * 16 + gl];
    int da = pa >> 20, db = pb >> 20, dc = pc >> 20, dd = pd >> 20;
    int ia = da * 64 + ((4 * (gl + da)) & 63);
    int ib = db * 64 + ((4 * (gl + db)) & 63);
    int ic = dc * 64 + ((4 * (gl + dc)) & 63);
    int id = dd * 64 + ((4 * (gl + dd)) & 63);
    atomicAdd(&acc[ia],     va.x); atomicAdd(&acc[ia + 1], va.y);
    atomicAdd(&acc[ia + 2], va.z); atomicAdd(&acc[ia + 3], va.w);
    atomicAdd(&acc[ib],     vb.x); atomicAdd(&acc[ib + 1], vb.y);
    atomicAdd(&acc[ib + 2], vb.z); atomicAdd(&acc[ib + 3], vb.w);
    atomicAdd(&acc[ic],     vc.x); atomicAdd(&acc[ic + 1], vc.y);
    atomicAdd(&acc[ic + 2], vc.z); atomicAdd(&acc[ic + 3], vc.w);
    atomicAdd(&acc[id],     vd.x); atomicAdd(&acc[id + 1], vd.y);
    atomicAdd(&acc[id + 2], vd.z); atomicAdd(&acc[id + 3], vd.w);
  }
  for (; e < p1; e += 16) {
    int p = pairBuf[e];
    float4 v = tab[(size_t)(p & 0xFFFFF) * 16 + gl];
    int dl = p >> 20;
    int ix = dl * 64 + ((4 * (gl + dl)) & 63);
    atomicAdd(&acc[ix],     v.x); atomicAdd(&acc[ix + 1], v.y);
    atomicAdd(&acc[ix + 2], v.z); atomicAdd(&acc[ix + 3], v.w);
  }
  __syncthreads();

  // epilogue: OUT[node][c] = dinv*acc + bias (coalesced)
  for (int i = tid; i < NPB * 64; i += TPB) {
    int dl = i >> 6, c = i & 63;
    int node = node0 + dl;
    if (node < n)
      OUT[(size_t)node * 64 + c] =
          dinv[node] * acc[dl * 64 + ((c + dl * 4) & 63)] + bias[c];
  }
}

// hws1[n] = (relu(H[n]) . Wo) * dinv[n]
__global__ __launch_bounds__(TPB) void k_fdot(const float* __restrict__ H,
                                              const float* __restrict__ Wo,
                                              const float* __restrict__ dinv,
                                              float* __restrict__ hws1, int n) {
  int i = blockIdx.x * TPB + threadIdx.x;
  if (i >= n) return;
  const float4* Hv = (const float4*)(H + (size_t)i * 64);
  float acc = 0.f;
#pragma unroll
  for (int q = 0; q < 16; ++q) {
    float4 v = Hv[q];
    acc += fmaxf(v.x, 0.f) * Wo[4 * q + 0];
    acc += fmaxf(v.y, 0.f) * Wo[4 * q + 1];
    acc += fmaxf(v.z, 0.f) * Wo[4 * q + 2];
    acc += fmaxf(v.w, 0.f) * Wo[4 * q + 3];
  }
  hws1[i] = acc * dinv[i];
}

// final 1-channel aggregation: bucket LDS acc over pairBuf (hws1 is 400KB,
// L2-resident on every XCD)
__global__ __launch_bounds__(TPB) void k_fscat1(const float* __restrict__ hws1,
                                                const int* __restrict__ pairBuf,
                                                const int* __restrict__ bOff,
                                                const float* __restrict__ dinv,
                                                const float* __restrict__ bo,
                                                float* __restrict__ out, int n) {
  __shared__ float a1[NPB];
  int b = blockIdx.x, t = threadIdx.x;
  int node0 = b << BSH;
  if (t < NPB) {
    int node = node0 + t;
    a1[t] = (node < n) ? hws1[node] : 0.f;   // self loop
  }
  __syncthreads();
  int p0 = bOff[b], p1 = bOff[b + 1];
  for (int i = p0 + t; i < p1; i += TPB) {
    int p = pairBuf[i];
    atomicAdd(&a1[p >> 20], hws1[p & 0xFFFFF]);
  }
  __syncthreads();
  if (t < NPB) {
    int node = node0 + t;
    if (node < n) out[node] = dinv[node] * a1[t] + bo[0];
  }
}

// ---------------- launch ----------------

extern "C" void kernel_launch(void* const* d_in, const int* in_sizes, int n_in,
                              void* d_out, int out_size, void* d_ws, size_t ws_size,
                              hipStream_t stream) {
  const float* x   = (const float*)d_in[0];
  const int*   ei  = (const int*)d_in[1];
  const float* W_i = (const float*)d_in[2];
  const float* b_i = (const float*)d_in[3];
  const float* W_h = (const float*)d_in[4];
  const float* b_h = (const float*)d_in[5];
  const float* W_o = (const float*)d_in[6];
  const float* b_o = (const float*)d_in[7];

  const int N = in_sizes[0] / 64;   // 100000
  const int E = in_sizes[1] / 2;    // 2000000
  const int* srcArr = ei;           // edge_index[0]
  const int* dstArr = ei + E;       // edge_index[1]
  const int nbuck = (N + NPB - 1) >> BSH;   // 782

  char* w = (char*)d_ws;
  auto take = [&](size_t bytes) -> char* {
    char* p = w;
    w += (bytes + 255) & ~(size_t)255;
    return p;
  };
  float* dinv      = (float*)take((size_t)N * 4);
  int*   bucketCnt = (int*)take((size_t)BMAX * 4);
  int*   bOff      = (int*)take((size_t)(BMAX + 1) * 4);
  int*   gCur      = (int*)take((size_t)BMAX * 4);
  int*   pairBuf   = (int*)take((size_t)E * 4);
  float* bufH      = (float*)take((size_t)N * 64 * 4);
  float* bufS      = (float*)take((size_t)N * 64 * 4);
  float* hws1      = (float*)take((size_t)N * 4);
  (void)ws_size; (void)n_in; (void)out_size;

  const int nbN    = (N + TPB - 1) / TPB;
  const int nbEd   = (E + EPB - 1) / EPB;
  const int nbGemm = (N + 63) / 64;

  // edge bucketing + dinv
  hipMemsetAsync(bucketCnt, 0, (size_t)BMAX * 4, stream);
  k_hist  <<<nbEd, TPB, 0, stream>>>(dstArr, bucketCnt, E, nbuck);
  k_bscan <<<1, BMAX, 0, stream>>>(bucketCnt, bOff, gCur, nbuck);
  k_bucket<<<nbEd, TPB, 0, stream>>>(srcArr, dstArr, gCur, pairBuf, E, nbuck);
  k_deg   <<<nbuck, TPB, 0, stream>>>(pairBuf, bOff, dinv, N);

  // layer 0: x -> bufS -> bufH
  k_gemm<<<nbGemm, TPB, 0, stream>>>(x, W_i, dinv, bufS, 0, N);
  k_agg <<<nbuck, TPB, 0, stream>>>(bufS, pairBuf, bOff, dinv, b_i, bufH, N);

  // 6 hidden layers
  for (int l = 0; l < 6; ++l) {
    k_gemm<<<nbGemm, TPB, 0, stream>>>(bufH, W_h + (size_t)l * 64 * 64, dinv, bufS, 1, N);
    k_agg <<<nbuck, TPB, 0, stream>>>(bufS, pairBuf, bOff, dinv, b_h + (size_t)l * 64, bufH, N);
  }

  // output layer: 64 -> 1
  k_fdot  <<<nbN, TPB, 0, stream>>>(bufH, W_o, dinv, hws1, N);
  k_fscat1<<<nbuck, TPB, 0, stream>>>(hws1, pairBuf, bOff, dinv, b_o, (float*)d_out, N);
}

// Round 9
// 5430.661 us; speedup vs baseline: 1.1333x; 1.1333x over previous
//
#include <hip/hip_runtime.h>
#include <math.h>

#define TPB 256
#define BSH 6                  // 64 nodes per bucket
#define NPB (1 << BSH)         // nodes per bucket
#define BMAX 2048              // max buckets (N <= 131072)
#define EPB 4096               // edges per block in hist/bucket passes
#define SORTN 2048             // max edges per bucket for in-LDS sort
#define SMSK 0xFFFFF           // src mask in packed pair

// ---------------- edge bucketing (no global random atomics) ----------------

// pass A: coarse histogram of dst by bucket
__global__ __launch_bounds__(TPB) void k_hist(const int* __restrict__ dst,
                                              int* __restrict__ bucketCnt,
                                              int nE, int nbuck) {
  __shared__ int h[BMAX];
  for (int i = threadIdx.x; i < BMAX; i += TPB) h[i] = 0;
  __syncthreads();
  int base = blockIdx.x * EPB;
  for (int i = threadIdx.x; i < EPB; i += TPB) {
    int e = base + i;
    if (e < nE) atomicAdd(&h[dst[e] >> BSH], 1);
  }
  __syncthreads();
  for (int i = threadIdx.x; i < nbuck; i += TPB)
    if (h[i]) atomicAdd(&bucketCnt[i], h[i]);
}

// pass B: scan bucket counts -> bOff[nbuck+1], init gCur (1024 thr, 2/thread)
__global__ __launch_bounds__(1024) void k_bscan(const int* __restrict__ bucketCnt,
                                                int* __restrict__ bOff,
                                                int* __restrict__ gCur,
                                                int nbuck) {
  __shared__ int sd[1024];
  int t = threadIdx.x;
  int i0 = 2 * t, i1 = 2 * t + 1;
  int v0 = (i0 < nbuck) ? bucketCnt[i0] : 0;
  int v1 = (i1 < nbuck) ? bucketCnt[i1] : 0;
  sd[t] = v0 + v1;
  __syncthreads();
  for (int off = 1; off < 1024; off <<= 1) {
    int add = (t >= off) ? sd[t - off] : 0;
    __syncthreads();
    sd[t] += add;
    __syncthreads();
  }
  int base = sd[t] - (v0 + v1);   // exclusive prefix for i0
  if (i0 < nbuck) { gCur[i0] = base;      bOff[i0 + 1] = base + v0; }
  if (i1 < nbuck) { gCur[i1] = base + v0; bOff[i1 + 1] = base + v0 + v1; }
  if (t == 0) bOff[0] = 0;
}

// pass C: scatter packed (src | dlocal<<20) into bucket-sorted pairBuf
__global__ __launch_bounds__(TPB) void k_bucket(const int* __restrict__ src,
                                                const int* __restrict__ dst,
                                                int* __restrict__ gCur,
                                                int* __restrict__ pairBuf,
                                                int nE, int nbuck) {
  __shared__ int   hist[BMAX];
  __shared__ int   baseL[BMAX];
  __shared__ int   sp[EPB];
  __shared__ short sbk[EPB];
  for (int i = threadIdx.x; i < BMAX; i += TPB) hist[i] = 0;
  __syncthreads();
  int cb = blockIdx.x * EPB;
  for (int i = threadIdx.x; i < EPB; i += TPB) {
    int e = cb + i;
    if (e < nE) {
      int s = src[e], d = dst[e];
      int b = d >> BSH;
      sp[i]  = s | ((d & (NPB - 1)) << 20);
      sbk[i] = (short)b;
      atomicAdd(&hist[b], 1);
    } else sbk[i] = -1;
  }
  __syncthreads();
  for (int i = threadIdx.x; i < nbuck; i += TPB)
    baseL[i] = hist[i] ? atomicAdd(&gCur[i], hist[i]) : 0;
  __syncthreads();
  for (int i = threadIdx.x; i < BMAX; i += TPB) hist[i] = 0;  // reuse as cursor
  __syncthreads();
  for (int i = threadIdx.x; i < EPB; i += TPB) {
    int b = sbk[i];
    if (b >= 0) {
      int r = atomicAdd(&hist[b], 1);
      pairBuf[baseL[b] + r] = sp[i];
    }
  }
}

// pass D: per-bucket degree histogram -> dinv
__global__ __launch_bounds__(TPB) void k_deg(const int* __restrict__ pairBuf,
                                             const int* __restrict__ bOff,
                                             float* __restrict__ dinv, int n) {
  __shared__ int h[NPB];
  int t = threadIdx.x;
  int b = blockIdx.x;
  if (t < NPB) h[t] = 0;
  __syncthreads();
  int p0 = bOff[b], p1 = bOff[b + 1];
  for (int i = p0 + t; i < p1; i += TPB)
    atomicAdd(&h[pairBuf[i] >> 20], 1);
  __syncthreads();
  if (t < NPB) {
    int node = (b << BSH) + t;
    if (node < n) dinv[node] = rsqrtf((float)(h[t] + 1));  // +1 self loop
  }
}

// pass E: per-bucket counting sort of pairs by src-range (src>>11).
// Perf-only (k_agg2/k_fscat1 are order-insensitive): aligns all blocks'
// gather streams into a common low->high sweep of the feature table so the
// live window (~1-2MB) stays L2-resident on every XCD.
__global__ __launch_bounds__(TPB) void k_sort(int* __restrict__ pairBuf,
                                              const int* __restrict__ bOff) {
  __shared__ int sp[SORTN];
  __shared__ int so[SORTN];
  __shared__ int hist[64], cur[64];
  int b = blockIdx.x, t = threadIdx.x;
  int p0 = bOff[b];
  int sz = bOff[b + 1] - p0;
  if (sz > SORTN) return;   // safety fallback: leave unsorted (still correct)
  if (t < 64) hist[t] = 0;
  __syncthreads();
  for (int i = t; i < sz; i += TPB) {
    int p = pairBuf[p0 + i];
    sp[i] = p;
    atomicAdd(&hist[(p & SMSK) >> 11], 1);
  }
  __syncthreads();
  if (t == 0) {
    int run = 0;
    for (int r = 0; r < 64; ++r) { cur[r] = run; run += hist[r]; }
  }
  __syncthreads();
  for (int i = t; i < sz; i += TPB) {
    int p = sp[i];
    int pos = atomicAdd(&cur[(p & SMSK) >> 11], 1);
    so[pos] = p;
  }
  __syncthreads();
  for (int i = t; i < sz; i += TPB) pairBuf[p0 + i] = so[i];
}

// ---------------- per-layer kernels (dense N x 64 row-major) ----------------

// HWS[n][c] = (act(H[n]) @ W)[c] * dinv[n]
__global__ __launch_bounds__(TPB, 4) void k_gemm(const float* __restrict__ H,
                                                 const float* __restrict__ W,
                                                 const float* __restrict__ dinv,
                                                 float* __restrict__ HWS,
                                                 int relu, int rows) {
  __shared__ float Wl[64 * 64];     // [k][c]
  __shared__ float Hl[64][68];      // [r][k], padded
  const int tid = threadIdx.x;
  const int c0 = (tid & 15) * 4;
  const int r0 = (tid >> 4) * 4;
  const int row0 = blockIdx.x * 64;

  for (int i = tid; i < 64 * 16; i += TPB)
    ((float4*)Wl)[i] = ((const float4*)W)[i];

  for (int i = tid; i < 64 * 16; i += TPB) {
    int r = i >> 4, q = i & 15;
    int gr = row0 + r;
    float4 v = make_float4(0.f, 0.f, 0.f, 0.f);
    if (gr < rows) v = ((const float4*)(H + (size_t)gr * 64))[q];
    if (relu) {
      v.x = fmaxf(v.x, 0.f); v.y = fmaxf(v.y, 0.f);
      v.z = fmaxf(v.z, 0.f); v.w = fmaxf(v.w, 0.f);
    }
    *(float4*)&Hl[r][q * 4] = v;
  }
  __syncthreads();

  float acc[4][4] = {{0.f,0.f,0.f,0.f},{0.f,0.f,0.f,0.f},
                     {0.f,0.f,0.f,0.f},{0.f,0.f,0.f,0.f}};
#pragma unroll 4
  for (int k = 0; k < 64; ++k) {
    float4 w = *(const float4*)&Wl[k * 64 + c0];
    float h0 = Hl[r0 + 0][k];
    float h1 = Hl[r0 + 1][k];
    float h2 = Hl[r0 + 2][k];
    float h3 = Hl[r0 + 3][k];
    acc[0][0] = fmaf(h0, w.x, acc[0][0]); acc[0][1] = fmaf(h0, w.y, acc[0][1]);
    acc[0][2] = fmaf(h0, w.z, acc[0][2]); acc[0][3] = fmaf(h0, w.w, acc[0][3]);
    acc[1][0] = fmaf(h1, w.x, acc[1][0]); acc[1][1] = fmaf(h1, w.y, acc[1][1]);
    acc[1][2] = fmaf(h1, w.z, acc[1][2]); acc[1][3] = fmaf(h1, w.w, acc[1][3]);
    acc[2][0] = fmaf(h2, w.x, acc[2][0]); acc[2][1] = fmaf(h2, w.y, acc[2][1]);
    acc[2][2] = fmaf(h2, w.z, acc[2][2]); acc[2][3] = fmaf(h2, w.w, acc[2][3]);
    acc[3][0] = fmaf(h3, w.x, acc[3][0]); acc[3][1] = fmaf(h3, w.y, acc[3][1]);
    acc[3][2] = fmaf(h3, w.z, acc[3][2]); acc[3][3] = fmaf(h3, w.w, acc[3][3]);
  }

#pragma unroll
  for (int i = 0; i < 4; ++i) {
    int gr = row0 + r0 + i;
    if (gr < rows) {
      float s = dinv[gr];
      float4 o = make_float4(acc[i][0] * s, acc[i][1] * s,
                             acc[i][2] * s, acc[i][3] * s);
      *(float4*)&HWS[(size_t)gr * 64 + c0] = o;
    }
  }
}

// Edge-parallel aggregation, one EDGE per WAVE instruction, lane = channel.
// acc[dl*64+c] for c=0..63 -> 64 consecutive floats -> 32 banks x 2-way =
// conflict-free ds_add_f32 (round-8 fix). Gather = 256B contiguous per wave.
// Edges are src-sorted (k_sort) -> all blocks sweep the table in phase.
__global__ __launch_bounds__(TPB) void k_agg2(const float* __restrict__ HWS,
                                              const int* __restrict__ pairBuf,
                                              const int* __restrict__ bOff,
                                              const float* __restrict__ dinv,
                                              const float* __restrict__ bias,
                                              float* __restrict__ OUT, int n) {
  __shared__ float acc[NPB * 64];   // 16KB
  const int b = blockIdx.x;
  const int tid = threadIdx.x;
  const int node0 = b << BSH;
  const float4* __restrict__ tab4 = (const float4*)HWS;

  // init with self-loop term (HWS already dinv-prescaled), coalesced float4
  for (int i = tid; i < NPB * 16; i += TPB) {
    int dl = i >> 4, q = i & 15;
    int node = node0 + dl;
    float4 v = make_float4(0.f, 0.f, 0.f, 0.f);
    if (node < n) v = tab4[(size_t)node * 16 + q];
    *(float4*)&acc[(dl << 6) + q * 4] = v;
  }
  __syncthreads();

  const int p0 = bOff[b], p1 = bOff[b + 1];
  const int c  = tid & 63;    // lane = channel
  const int wv = tid >> 6;    // 4 waves interleave consecutive edges (stride 4)

  int e = p0 + wv;
  for (; e + 28 < p1; e += 32) {     // 8 edges per wave per iter
    int q0 = pairBuf[e];
    int q1 = pairBuf[e + 4];
    int q2 = pairBuf[e + 8];
    int q3 = pairBuf[e + 12];
    int q4 = pairBuf[e + 16];
    int q5 = pairBuf[e + 20];
    int q6 = pairBuf[e + 24];
    int q7 = pairBuf[e + 28];
    float v0 = HWS[(size_t)(q0 & SMSK) * 64 + c];
    float v1 = HWS[(size_t)(q1 & SMSK) * 64 + c];
    float v2 = HWS[(size_t)(q2 & SMSK) * 64 + c];
    float v3 = HWS[(size_t)(q3 & SMSK) * 64 + c];
    float v4 = HWS[(size_t)(q4 & SMSK) * 64 + c];
    float v5 = HWS[(size_t)(q5 & SMSK) * 64 + c];
    float v6 = HWS[(size_t)(q6 & SMSK) * 64 + c];
    float v7 = HWS[(size_t)(q7 & SMSK) * 64 + c];
    atomicAdd(&acc[((q0 >> 20) << 6) + c], v0);
    atomicAdd(&acc[((q1 >> 20) << 6) + c], v1);
    atomicAdd(&acc[((q2 >> 20) << 6) + c], v2);
    atomicAdd(&acc[((q3 >> 20) << 6) + c], v3);
    atomicAdd(&acc[((q4 >> 20) << 6) + c], v4);
    atomicAdd(&acc[((q5 >> 20) << 6) + c], v5);
    atomicAdd(&acc[((q6 >> 20) << 6) + c], v6);
    atomicAdd(&acc[((q7 >> 20) << 6) + c], v7);
  }
  for (; e < p1; e += 4) {
    int q = pairBuf[e];
    float v = HWS[(size_t)(q & SMSK) * 64 + c];
    atomicAdd(&acc[((q >> 20) << 6) + c], v);
  }
  __syncthreads();

  // epilogue: OUT[node][c] = dinv*acc + bias, coalesced float4
  for (int i = tid; i < NPB * 16; i += TPB) {
    int dl = i >> 4, q = i & 15;
    int node = node0 + dl;
    if (node < n) {
      float s = dinv[node];
      float4 a  = *(float4*)&acc[(dl << 6) + q * 4];
      float4 bb = *(const float4*)&bias[q * 4];
      *(float4*)&OUT[(size_t)node * 64 + q * 4] =
          make_float4(a.x * s + bb.x, a.y * s + bb.y,
                      a.z * s + bb.z, a.w * s + bb.w);
    }
  }
}

// hws1[n] = (relu(H[n]) . Wo) * dinv[n]
__global__ __launch_bounds__(TPB) void k_fdot(const float* __restrict__ H,
                                              const float* __restrict__ Wo,
                                              const float* __restrict__ dinv,
                                              float* __restrict__ hws1, int n) {
  int i = blockIdx.x * TPB + threadIdx.x;
  if (i >= n) return;
  const float4* Hv = (const float4*)(H + (size_t)i * 64);
  float acc = 0.f;
#pragma unroll
  for (int q = 0; q < 16; ++q) {
    float4 v = Hv[q];
    acc += fmaxf(v.x, 0.f) * Wo[4 * q + 0];
    acc += fmaxf(v.y, 0.f) * Wo[4 * q + 1];
    acc += fmaxf(v.z, 0.f) * Wo[4 * q + 2];
    acc += fmaxf(v.w, 0.f) * Wo[4 * q + 3];
  }
  hws1[i] = acc * dinv[i];
}

// final 1-channel aggregation over pairBuf (hws1 = 400KB, L2-resident)
__global__ __launch_bounds__(TPB) void k_fscat1(const float* __restrict__ hws1,
                                                const int* __restrict__ pairBuf,
                                                const int* __restrict__ bOff,
                                                const float* __restrict__ dinv,
                                                const float* __restrict__ bo,
                                                float* __restrict__ out, int n) {
  __shared__ float a1[NPB];
  int b = blockIdx.x, t = threadIdx.x;
  int node0 = b << BSH;
  if (t < NPB) {
    int node = node0 + t;
    a1[t] = (node < n) ? hws1[node] : 0.f;   // self loop
  }
  __syncthreads();
  int p0 = bOff[b], p1 = bOff[b + 1];
  for (int i = p0 + t; i < p1; i += TPB) {
    int p = pairBuf[i];
    atomicAdd(&a1[p >> 20], hws1[p & SMSK]);
  }
  __syncthreads();
  if (t < NPB) {
    int node = node0 + t;
    if (node < n) out[node] = dinv[node] * a1[t] + bo[0];
  }
}

// ---------------- launch ----------------

extern "C" void kernel_launch(void* const* d_in, const int* in_sizes, int n_in,
                              void* d_out, int out_size, void* d_ws, size_t ws_size,
                              hipStream_t stream) {
  const float* x   = (const float*)d_in[0];
  const int*   ei  = (const int*)d_in[1];
  const float* W_i = (const float*)d_in[2];
  const float* b_i = (const float*)d_in[3];
  const float* W_h = (const float*)d_in[4];
  const float* b_h = (const float*)d_in[5];
  const float* W_o = (const float*)d_in[6];
  const float* b_o = (const float*)d_in[7];

  const int N = in_sizes[0] / 64;   // 100000
  const int E = in_sizes[1] / 2;    // 2000000
  const int* srcArr = ei;           // edge_index[0]
  const int* dstArr = ei + E;       // edge_index[1]
  const int nbuck = (N + NPB - 1) >> BSH;   // 1563

  char* w = (char*)d_ws;
  auto take = [&](size_t bytes) -> char* {
    char* p = w;
    w += (bytes + 255) & ~(size_t)255;
    return p;
  };
  float* dinv      = (float*)take((size_t)N * 4);
  int*   bucketCnt = (int*)take((size_t)BMAX * 4);
  int*   bOff      = (int*)take((size_t)(BMAX + 1) * 4);
  int*   gCur      = (int*)take((size_t)BMAX * 4);
  int*   pairBuf   = (int*)take((size_t)E * 4);
  float* bufH      = (float*)take((size_t)N * 64 * 4);
  float* bufS      = (float*)take((size_t)N * 64 * 4);
  float* hws1      = (float*)take((size_t)N * 4);
  (void)ws_size; (void)n_in; (void)out_size;

  const int nbN    = (N + TPB - 1) / TPB;
  const int nbEd   = (E + EPB - 1) / EPB;
  const int nbGemm = (N + 63) / 64;

  // edge bucketing + dinv + per-bucket src-sort
  hipMemsetAsync(bucketCnt, 0, (size_t)BMAX * 4, stream);
  k_hist  <<<nbEd, TPB, 0, stream>>>(dstArr, bucketCnt, E, nbuck);
  k_bscan <<<1, 1024, 0, stream>>>(bucketCnt, bOff, gCur, nbuck);
  k_bucket<<<nbEd, TPB, 0, stream>>>(srcArr, dstArr, gCur, pairBuf, E, nbuck);
  k_deg   <<<nbuck, TPB, 0, stream>>>(pairBuf, bOff, dinv, N);
  k_sort  <<<nbuck, TPB, 0, stream>>>(pairBuf, bOff);

  // layer 0: x -> bufS -> bufH
  k_gemm<<<nbGemm, TPB, 0, stream>>>(x, W_i, dinv, bufS, 0, N);
  k_agg2<<<nbuck, TPB, 0, stream>>>(bufS, pairBuf, bOff, dinv, b_i, bufH, N);

  // 6 hidden layers
  for (int l = 0; l < 6; ++l) {
    k_gemm<<<nbGemm, TPB, 0, stream>>>(bufH, W_h + (size_t)l * 64 * 64, dinv, bufS, 1, N);
    k_agg2<<<nbuck, TPB, 0, stream>>>(bufS, pairBuf, bOff, dinv, b_h + (size_t)l * 64, bufH, N);
  }

  // output layer: 64 -> 1
  k_fdot  <<<nbN, TPB, 0, stream>>>(bufH, W_o, dinv, hws1, N);
  k_fscat1<<<nbuck, TPB, 0, stream>>>(hws1, pairBuf, bOff, dinv, b_o, (float*)d_out, N);
}

// Round 10
// 728.749 us; speedup vs baseline: 8.4454x; 7.4520x over previous
//
#include <hip/hip_runtime.h>
#include <math.h>

#define TPB 256
#define BSH 8                  // 256 nodes per bucket (TPB must equal 1<<BSH)
#define BMAX 512               // max buckets (N <= 131072)
#define EPB 4096               // edges per block in hist/bucket passes

typedef float __attribute__((ext_vector_type(4))) f32x4;

static __device__ __forceinline__ void nt_store4(float* p, float x, float y,
                                                 float z, float w) {
  f32x4 v = {x, y, z, w};
  __builtin_nontemporal_store(v, (f32x4*)p);
}
static __device__ __forceinline__ int nt_load_i(const int* p) {
  return __builtin_nontemporal_load(p);
}

// ---------------- CSR build (bucketed, no global random atomics) ----------------

__global__ __launch_bounds__(TPB) void k_hist(const int* __restrict__ dst,
                                              int* __restrict__ bucketCnt,
                                              int nE, int nbuck) {
  __shared__ int h[BMAX];
  for (int i = threadIdx.x; i < BMAX; i += TPB) h[i] = 0;
  __syncthreads();
  int base = blockIdx.x * EPB;
  for (int i = threadIdx.x; i < EPB; i += TPB) {
    int e = base + i;
    if (e < nE) atomicAdd(&h[dst[e] >> BSH], 1);
  }
  __syncthreads();
  for (int i = threadIdx.x; i < nbuck; i += TPB)
    if (h[i]) atomicAdd(&bucketCnt[i], h[i]);
}

__global__ __launch_bounds__(BMAX) void k_bscan(const int* __restrict__ bucketCnt,
                                                int* __restrict__ bOff,
                                                int* __restrict__ gCur,
                                                int* __restrict__ rowPtr,
                                                int nbuck, int n, int nE) {
  __shared__ int sd[BMAX];
  int t = threadIdx.x;
  int v = (t < nbuck) ? bucketCnt[t] : 0;
  sd[t] = v;
  __syncthreads();
  for (int off = 1; off < BMAX; off <<= 1) {
    int add = (t >= off) ? sd[t - off] : 0;
    __syncthreads();
    sd[t] += add;
    __syncthreads();
  }
  if (t < nbuck) {
    bOff[t + 1] = sd[t];
    gCur[t] = sd[t] - v;     // exclusive prefix
  }
  if (t == 0) { bOff[0] = 0; rowPtr[n] = nE; }
}

__global__ __launch_bounds__(TPB) void k_bucket(const int* __restrict__ src,
                                                const int* __restrict__ dst,
                                                int* __restrict__ gCur,
                                                int* __restrict__ pairBuf,
                                                int nE, int nbuck) {
  __shared__ int   hist[BMAX];
  __shared__ int   baseL[BMAX];
  __shared__ int   sp[EPB];
  __shared__ short sbk[EPB];
  for (int i = threadIdx.x; i < BMAX; i += TPB) hist[i] = 0;
  __syncthreads();
  int cb = blockIdx.x * EPB;
  for (int i = threadIdx.x; i < EPB; i += TPB) {
    int e = cb + i;
    if (e < nE) {
      int s = src[e], d = dst[e];
      int b = d >> BSH;
      sp[i]  = s | ((d & ((1 << BSH) - 1)) << 20);
      sbk[i] = (short)b;
      atomicAdd(&hist[b], 1);
    } else sbk[i] = -1;
  }
  __syncthreads();
  for (int i = threadIdx.x; i < nbuck; i += TPB)
    baseL[i] = hist[i] ? atomicAdd(&gCur[i], hist[i]) : 0;
  __syncthreads();
  for (int i = threadIdx.x; i < BMAX; i += TPB) hist[i] = 0;  // reuse as cursor
  __syncthreads();
  for (int i = threadIdx.x; i < EPB; i += TPB) {
    int b = sbk[i];
    if (b >= 0) {
      int r = atomicAdd(&hist[b], 1);
      pairBuf[baseL[b] + r] = sp[i];
    }
  }
}

__global__ __launch_bounds__(TPB) void k_final(const int* __restrict__ pairBuf,
                                               const int* __restrict__ bOff,
                                               int* __restrict__ rowPtr,
                                               int* __restrict__ col,
                                               float* __restrict__ dinv,
                                               int n) {
  __shared__ int h[TPB];
  __shared__ int ex[TPB];
  int t = threadIdx.x;
  int b = blockIdx.x;
  int p0 = bOff[b], p1 = bOff[b + 1];
  h[t] = 0;
  __syncthreads();
  for (int i = p0 + t; i < p1; i += TPB)
    atomicAdd(&h[pairBuf[i] >> 20], 1);
  __syncthreads();
  int v = h[t];
  ex[t] = v;
  __syncthreads();
  for (int off = 1; off < TPB; off <<= 1) {
    int add = (t >= off) ? ex[t - off] : 0;
    __syncthreads();
    ex[t] += add;
    __syncthreads();
  }
  int excl = ex[t] - v;
  int node = (b << BSH) + t;
  if (node < n) {
    rowPtr[node] = p0 + excl;
    dinv[node]   = rsqrtf((float)(v + 1));  // +1 self loop
  }
  __syncthreads();
  h[t] = excl;  // reuse as per-local-node cursor
  __syncthreads();
  for (int i = p0 + t; i < p1; i += TPB) {
    int p = pairBuf[i];
    int r = atomicAdd(&h[p >> 20], 1);
    col[p0 + r] = p & 0xFFFFF;
  }
}

// ---------------- per-layer kernels ----------------

// HWS[n][c] = (act(H[n]) @ W)[c] * dinv[n]; HWS written nontemporal (read
// later, randomly, by scatter — no benefit leaving the write in L2).
__global__ __launch_bounds__(TPB, 4) void k_gemm(const float* __restrict__ H,
                                                 const float* __restrict__ W,
                                                 const float* __restrict__ dinv,
                                                 float* __restrict__ HWS,
                                                 int relu, int rows) {
  __shared__ float Wl[64 * 64];     // [k][c]
  __shared__ float Hl[64][68];      // [r][k], padded
  const int tid = threadIdx.x;
  const int c0 = (tid & 15) * 4;
  const int r0 = (tid >> 4) * 4;
  const int row0 = blockIdx.x * 64;

  for (int i = tid; i < 64 * 16; i += TPB)
    ((float4*)Wl)[i] = ((const float4*)W)[i];

  for (int i = tid; i < 64 * 16; i += TPB) {
    int r = i >> 4, q = i & 15;
    int gr = row0 + r;
    float4 v = make_float4(0.f, 0.f, 0.f, 0.f);
    if (gr < rows) v = ((const float4*)(H + (size_t)gr * 64))[q];
    if (relu) {
      v.x = fmaxf(v.x, 0.f); v.y = fmaxf(v.y, 0.f);
      v.z = fmaxf(v.z, 0.f); v.w = fmaxf(v.w, 0.f);
    }
    *(float4*)&Hl[r][q * 4] = v;
  }
  __syncthreads();

  float acc[4][4] = {{0.f,0.f,0.f,0.f},{0.f,0.f,0.f,0.f},
                     {0.f,0.f,0.f,0.f},{0.f,0.f,0.f,0.f}};
#pragma unroll 4
  for (int k = 0; k < 64; ++k) {
    float4 w = *(const float4*)&Wl[k * 64 + c0];
    float h0 = Hl[r0 + 0][k];
    float h1 = Hl[r0 + 1][k];
    float h2 = Hl[r0 + 2][k];
    float h3 = Hl[r0 + 3][k];
    acc[0][0] = fmaf(h0, w.x, acc[0][0]); acc[0][1] = fmaf(h0, w.y, acc[0][1]);
    acc[0][2] = fmaf(h0, w.z, acc[0][2]); acc[0][3] = fmaf(h0, w.w, acc[0][3]);
    acc[1][0] = fmaf(h1, w.x, acc[1][0]); acc[1][1] = fmaf(h1, w.y, acc[1][1]);
    acc[1][2] = fmaf(h1, w.z, acc[1][2]); acc[1][3] = fmaf(h1, w.w, acc[1][3]);
    acc[2][0] = fmaf(h2, w.x, acc[2][0]); acc[2][1] = fmaf(h2, w.y, acc[2][1]);
    acc[2][2] = fmaf(h2, w.z, acc[2][2]); acc[2][3] = fmaf(h2, w.w, acc[2][3]);
    acc[3][0] = fmaf(h3, w.x, acc[3][0]); acc[3][1] = fmaf(h3, w.y, acc[3][1]);
    acc[3][2] = fmaf(h3, w.z, acc[3][2]); acc[3][3] = fmaf(h3, w.w, acc[3][3]);
  }

#pragma unroll
  for (int i = 0; i < 4; ++i) {
    int gr = row0 + r0 + i;
    if (gr < rows) {
      float s = dinv[gr];
      nt_store4(&HWS[(size_t)gr * 64 + c0],
                acc[i][0] * s, acc[i][1] * s, acc[i][2] * s, acc[i][3] * s);
    }
  }
}

// OUT[n][c] = dinv[n] * (HWS[n][c] + sum_{e in row n} HWS[col[e]][c]) + bias[c]
// Wave per node; lane = (edge-slot eg, channel-quad q); dwordx4 gathers pull
// 4 full 256B rows per instruction. col reads + OUT writes are NONTEMPORAL so
// the streaming data doesn't evict the gather-hot HWS table from L2.
// All __shfl in wave-uniform control flow (CDNA ds_bpermute returns undefined
// data from exec-inactive source lanes — round-4 bug).
__global__ __launch_bounds__(TPB) void k_scatter(const float* __restrict__ HWS,
                                                 const int* __restrict__ rowPtr,
                                                 const int* __restrict__ col,
                                                 const float* __restrict__ dinv,
                                                 const float* __restrict__ bias,
                                                 float* __restrict__ OUT, int n) {
  int wave = blockIdx.x * (TPB / 64) + (threadIdx.x >> 6);
  if (wave >= n) return;
  const int lane = threadIdx.x & 63;
  const int eg = lane >> 4;   // edge slot 0..3
  const int q  = lane & 15;   // channel quad
  const int node = wave;

  float4 acc = make_float4(0.f, 0.f, 0.f, 0.f);
  if (eg == 0)  // self loop counted once
    acc = *(const float4*)&HWS[(size_t)node * 64 + q * 4];

  const int e0 = rowPtr[node];
  const int deg = rowPtr[node + 1] - e0;

  for (int base = 0; base < deg; base += 64) {
    int m = deg - base; if (m > 64) m = 64;
    int idxv = (lane < m) ? nt_load_i(&col[e0 + base + lane]) : 0;
    int j = 0;
    // uniform trip counts: all 64 lanes active at every __shfl below
    for (; j + 16 <= m; j += 16) {
      int s0 = __shfl(idxv, j + eg,      64);
      int s1 = __shfl(idxv, j + 4 + eg,  64);
      int s2 = __shfl(idxv, j + 8 + eg,  64);
      int s3 = __shfl(idxv, j + 12 + eg, 64);
      float4 v0 = *(const float4*)&HWS[(size_t)s0 * 64 + q * 4];
      float4 v1 = *(const float4*)&HWS[(size_t)s1 * 64 + q * 4];
      float4 v2 = *(const float4*)&HWS[(size_t)s2 * 64 + q * 4];
      float4 v3 = *(const float4*)&HWS[(size_t)s3 * 64 + q * 4];
      acc.x += (v0.x + v1.x) + (v2.x + v3.x);
      acc.y += (v0.y + v1.y) + (v2.y + v3.y);
      acc.z += (v0.z + v1.z) + (v2.z + v3.z);
      acc.w += (v0.w + v1.w) + (v2.w + v3.w);
    }
    for (; j + 8 <= m; j += 8) {
      int s0 = __shfl(idxv, j + eg,     64);
      int s1 = __shfl(idxv, j + 4 + eg, 64);
      float4 v0 = *(const float4*)&HWS[(size_t)s0 * 64 + q * 4];
      float4 v1 = *(const float4*)&HWS[(size_t)s1 * 64 + q * 4];
      acc.x += v0.x + v1.x;
      acc.y += v0.y + v1.y;
      acc.z += v0.z + v1.z;
      acc.w += v0.w + v1.w;
    }
    for (; j < m; j += 4) {
      int jj = j + eg;
      int jc = (jj < m) ? jj : (m - 1);     // clamp: source lane always < m
      int s = __shfl(idxv, jc, 64);         // executed by ALL lanes (uniform)
      if (jj < m) {                         // only the gather is predicated
        float4 v = *(const float4*)&HWS[(size_t)s * 64 + q * 4];
        acc.x += v.x; acc.y += v.y; acc.z += v.z; acc.w += v.w;
      }
    }
  }

  // reduce across the 4 edge slots (lanes q, q+16, q+32, q+48)
#pragma unroll
  for (int off = 16; off < 64; off <<= 1) {
    acc.x += __shfl_xor(acc.x, off, 64);
    acc.y += __shfl_xor(acc.y, off, 64);
    acc.z += __shfl_xor(acc.z, off, 64);
    acc.w += __shfl_xor(acc.w, off, 64);
  }

  if (eg == 0) {
    float s = dinv[node];
    float4 b4 = *(const float4*)&bias[q * 4];
    nt_store4(&OUT[(size_t)node * 64 + q * 4],
              acc.x * s + b4.x, acc.y * s + b4.y,
              acc.z * s + b4.z, acc.w * s + b4.w);
  }
}

// hws1[n] = (relu(H[n]) . Wo) * dinv[n]
__global__ __launch_bounds__(TPB) void k_fdot(const float* __restrict__ H,
                                              const float* __restrict__ Wo,
                                              const float* __restrict__ dinv,
                                              float* __restrict__ hws1, int n) {
  int i = blockIdx.x * TPB + threadIdx.x;
  if (i >= n) return;
  const float4* Hv = (const float4*)(H + (size_t)i * 64);
  float acc = 0.f;
#pragma unroll
  for (int q = 0; q < 16; ++q) {
    float4 v = Hv[q];
    acc += fmaxf(v.x, 0.f) * Wo[4 * q + 0];
    acc += fmaxf(v.y, 0.f) * Wo[4 * q + 1];
    acc += fmaxf(v.z, 0.f) * Wo[4 * q + 2];
    acc += fmaxf(v.w, 0.f) * Wo[4 * q + 3];
  }
  hws1[i] = acc * dinv[i];
}

__global__ __launch_bounds__(TPB) void k_fscat(const float* __restrict__ hws1,
                                               const int* __restrict__ rowPtr,
                                               const int* __restrict__ col,
                                               const float* __restrict__ dinv,
                                               const float* __restrict__ bo,
                                               float* __restrict__ out, int n) {
  int i = blockIdx.x * TPB + threadIdx.x;
  if (i >= n) return;
  float a0 = hws1[i], a1 = 0.f, a2 = 0.f, a3 = 0.f;
  int e0 = rowPtr[i], e1 = rowPtr[i + 1];
  int e = e0;
  for (; e + 4 <= e1; e += 4) {
    a0 += hws1[nt_load_i(&col[e])];
    a1 += hws1[nt_load_i(&col[e + 1])];
    a2 += hws1[nt_load_i(&col[e + 2])];
    a3 += hws1[nt_load_i(&col[e + 3])];
  }
  for (; e < e1; ++e) a0 += hws1[nt_load_i(&col[e])];
  float r = dinv[i] * ((a0 + a1) + (a2 + a3)) + bo[0];
  __builtin_nontemporal_store(r, &out[i]);
}

// ---------------- launch ----------------

extern "C" void kernel_launch(void* const* d_in, const int* in_sizes, int n_in,
                              void* d_out, int out_size, void* d_ws, size_t ws_size,
                              hipStream_t stream) {
  const float* x   = (const float*)d_in[0];
  const int*   ei  = (const int*)d_in[1];
  const float* W_i = (const float*)d_in[2];
  const float* b_i = (const float*)d_in[3];
  const float* W_h = (const float*)d_in[4];
  const float* b_h = (const float*)d_in[5];
  const float* W_o = (const float*)d_in[6];
  const float* b_o = (const float*)d_in[7];

  const int N = in_sizes[0] / 64;   // 100000
  const int E = in_sizes[1] / 2;    // 2000000
  const int* srcArr = ei;           // edge_index[0]
  const int* dstArr = ei + E;       // edge_index[1]
  const int nbuck = (N + (1 << BSH) - 1) >> BSH;   // 391

  char* w = (char*)d_ws;
  auto take = [&](size_t bytes) -> char* {
    char* p = w;
    w += (bytes + 255) & ~(size_t)255;
    return p;
  };
  int*   rowPtr    = (int*)take((size_t)(N + 1) * 4);
  int*   col       = (int*)take((size_t)E * 4);
  float* dinv      = (float*)take((size_t)N * 4);
  int*   bucketCnt = (int*)take((size_t)BMAX * 4);
  int*   bOff      = (int*)take((size_t)(BMAX + 1) * 4);
  int*   gCur      = (int*)take((size_t)BMAX * 4);
  float* bufH      = (float*)take((size_t)N * 64 * 4);
  float* bufS      = (float*)take((size_t)N * 64 * 4);
  float* hws1      = (float*)take((size_t)N * 4);
  int*   pairBuf   = (int*)bufS;   // alias: bufS unused during CSR build
  (void)ws_size; (void)n_in; (void)out_size;

  const int nbN    = (N + TPB - 1) / TPB;
  const int nbEd   = (E + EPB - 1) / EPB;
  const int nbGemm = (N + 63) / 64;
  const int nbScat = (N + 3) / 4;  // 4 waves per block

  // CSR build + dinv
  hipMemsetAsync(bucketCnt, 0, (size_t)BMAX * 4, stream);
  k_hist  <<<nbEd, TPB, 0, stream>>>(dstArr, bucketCnt, E, nbuck);
  k_bscan <<<1, BMAX, 0, stream>>>(bucketCnt, bOff, gCur, rowPtr, nbuck, N, E);
  k_bucket<<<nbEd, TPB, 0, stream>>>(srcArr, dstArr, gCur, pairBuf, E, nbuck);
  k_final <<<nbuck, TPB, 0, stream>>>(pairBuf, bOff, rowPtr, col, dinv, N);

  // layer 0: x -> bufS -> bufH
  k_gemm   <<<nbGemm, TPB, 0, stream>>>(x, W_i, dinv, bufS, 0, N);
  k_scatter<<<nbScat, TPB, 0, stream>>>(bufS, rowPtr, col, dinv, b_i, bufH, N);

  // 6 hidden layers
  for (int l = 0; l < 6; ++l) {
    k_gemm   <<<nbGemm, TPB, 0, stream>>>(bufH, W_h + (size_t)l * 64 * 64, dinv, bufS, 1, N);
    k_scatter<<<nbScat, TPB, 0, stream>>>(bufS, rowPtr, col, dinv, b_h + (size_t)l * 64, bufH, N);
  }

  // output layer: 64 -> 1
  k_fdot <<<nbN, TPB, 0, stream>>>(bufH, W_o, dinv, hws1, N);
  k_fscat<<<nbN, TPB, 0, stream>>>(hws1, rowPtr, col, dinv, b_o, (float*)d_out, N);
}